// Round 6
// baseline (74.488 us; speedup 1.0000x reference)
//
#include <hip/hip_runtime.h>
#include <hip/hip_bf16.h>
#include <math.h>

#define BB 2
#define NN 512
#define KK 128
#define EE 768
#define NUM_EDGES 1536
#define MR 8   // rows per merge block

#define WS_REQ_BYTES ((size_t)(BB * NN * KK) * 4)

// ---------------- kernel 1: fused main (phases A+B+C), sums -> ws ----------------
// one block per (b,i) row, 256 threads
__global__ __launch_bounds__(256) void edge_main_kernel(
    const float* __restrict__ pos,
    const int* __restrict__ node_type_edge,
    const int* __restrict__ padding_mask,
    const int* __restrict__ mask_aa,
    const int* __restrict__ mask_pos,
    const int* __restrict__ time_pos,
    const float* __restrict__ means,
    const float* __restrict__ stds,
    const float* __restrict__ mul_w,
    const float* __restrict__ bias_w,
    const float* __restrict__ t_w1, const float* __restrict__ t_b1,
    const float* __restrict__ t_w2, const float* __restrict__ t_b2,
    float* __restrict__ ws_sums,         // [B*N][K]
    float* __restrict__ out_ef,          // [B,N,N,K]
    float* __restrict__ out_dp)          // [B,N,N,3]
{
    __shared__ float e2[2][KK];
    __shared__ float h2[2][KK];
    __shared__ float tv[2][KK];          // tv[0]=2*t_enc(t_b), tv[1]=2*t_enc(0)
    __shared__ float xv[NN];             // mul*dist+bias per j
    __shared__ unsigned char fl[NN];     // bit0: mask_dist, bit1: padded j
    __shared__ float red[8 * KK];        // j-group partial sums (4 KB)

    const int bi = blockIdx.x;
    const int b = bi >> 9;
    const int i = bi & (NN - 1);
    const int tid = threadIdx.x;

    // ---- phase A: time encodings, redundant per block (hidden by 1024-block TLP).
    //      threads 0..127 -> enc 0 (t=time_pos[b]), threads 128..255 -> enc 1 (t=0)
    {
        const int enc = tid >> 7;
        const int k = tid & 127;
        const float t = (enc == 0) ? (float)time_pos[b] : 0.0f;
        const int kk = k & 63;
        const float freq = __expf(-logf(10000.0f) * (float)kk * (1.0f / 64.0f));
        const float arg = t * freq;
        e2[enc][k] = (k < 64) ? cosf(arg) : sinf(arg);
        __syncthreads();

        float acc = t_b1[k];
#pragma unroll 8
        for (int r = 0; r < KK; ++r) acc += e2[enc][r] * t_w1[r * KK + k];
        h2[enc][k] = acc / (1.0f + __expf(-acc));   // SiLU
        __syncthreads();

        float acc2 = t_b2[k];
#pragma unroll 8
        for (int r = 0; r < KK; ++r) acc2 += h2[enc][r] * t_w2[r * KK + k];
        tv[enc][k] = 2.0f * acc2;
    }

    // ---- phase B: per-j quantities + delta_pos output ----
    const float pix = pos[(b * NN + i) * 3 + 0];
    const float piy = pos[(b * NN + i) * 3 + 1];
    const float piz = pos[(b * NN + i) * 3 + 2];
    const int maa_i  = mask_aa[b * NN + i];
    const int mpos_i = mask_pos[b * NN + i];

    for (int j = tid; j < NN; j += 256) {
        const float dx = pos[(b * NN + j) * 3 + 0] - pix;
        const float dy = pos[(b * NN + j) * 3 + 1] - piy;
        const float dz = pos[(b * NN + j) * 3 + 2] - piz;
        const float dist = sqrtf(dx * dx + dy * dy + dz * dz);
        const float invd = 1.0f / (dist + 1e-5f);
        const size_t dpo = ((size_t)bi * NN + j) * 3;
        out_dp[dpo + 0] = dx * invd;
        out_dp[dpo + 1] = dy * invd;
        out_dp[dpo + 2] = dz * invd;

        const int base = (bi * NN + j) * 2;
        int e0 = node_type_edge[base + 0];
        int e1 = node_type_edge[base + 1];
        if (maa_i)               e0 = 0;
        if (mask_aa[b * NN + j]) e1 = 0;
        const float mul  = mul_w[e0]  + mul_w[e1];
        const float bias = bias_w[e0] + bias_w[e1];
        xv[j] = mul * dist + bias;

        const int md  = (mpos_i | mask_pos[b * NN + j]) ? 1 : 0;
        const int pad = padding_mask[b * NN + j] ? 2 : 0;
        fl[j] = (unsigned char)(md | pad);
    }
    __syncthreads();   // orders tv/xv/fl writes before phase C reads

    // ---- phase C: each thread owns 4 consecutive k, 8 j-groups, float4 stores ----
    const int k0 = (tid & 31) * 4;
    const int jg = tid >> 5;             // 0..7
    const float a = sqrtf(2.0f * 3.14159f);

    float mean[4], inv[4], coef[4], t2[4], t02[4];
#pragma unroll
    for (int q = 0; q < 4; ++q) {
        mean[q] = means[k0 + q];
        const float sd = fabsf(stds[k0 + q]) + 0.01f;
        inv[q]  = 1.0f / sd;
        coef[q] = 1.0f / (a * sd);
        t2[q]   = tv[0][k0 + q];
        t02[q]  = tv[1][k0 + q];
    }

    float s[4] = {0.0f, 0.0f, 0.0f, 0.0f};
    const size_t efbase = (size_t)bi * NN * KK;

    for (int jj = 0; jj < NN / 8; ++jj) {
        const int j = jj * 8 + jg;
        const float x = xv[j];
        const unsigned char f = fl[j];
        float v[4];
#pragma unroll
        for (int q = 0; q < 4; ++q) {
            const float u = (x - mean[q]) * inv[q];
            float val = __expf(-0.5f * u * u) * coef[q] + ((f & 1) ? t2[q] : t02[q]);
            if (f & 2) val = 0.0f;
            s[q] += val;
            v[q] = val;
        }
        float4 st; st.x = v[0]; st.y = v[1]; st.z = v[2]; st.w = v[3];
        *reinterpret_cast<float4*>(&out_ef[efbase + (size_t)j * KK + k0]) = st;
    }

#pragma unroll
    for (int q = 0; q < 4; ++q) red[jg * KK + k0 + q] = s[q];
    __syncthreads();

    if (tid < KK) {
        float t = 0.0f;
#pragma unroll
        for (int g = 0; g < 8; ++g) t += red[g * KK + tid];
        ws_sums[(size_t)bi * KK + tid] = t;
    }
}

// ---------------- kernel 2: merge = sums @ proj_w + proj_b (tiled) ----------------
__global__ __launch_bounds__(256) void merge_tiled_kernel(
    const float* __restrict__ ws_sums,
    const float* __restrict__ proj_w,  // [K,E]
    const float* __restrict__ proj_b,  // [E]
    const int* __restrict__ padding_mask,
    float* __restrict__ out_merge)     // [B,N,E]
{
    __shared__ float s[MR][KK];
    __shared__ int pad[MR];
    const int row0 = blockIdx.x * MR;   // global row index (b*N+i)
    const int tid = threadIdx.x;

    for (int idx = tid; idx < MR * KK; idx += 256)
        s[idx >> 7][idx & 127] = ws_sums[(size_t)row0 * KK + idx];
    if (tid < MR) pad[tid] = padding_mask[row0 + tid];
    __syncthreads();

    const int e0 = tid, e1 = tid + 256, e2 = tid + 512;
    float acc0[MR], acc1[MR], acc2[MR];
#pragma unroll
    for (int m = 0; m < MR; ++m) { acc0[m] = 0.0f; acc1[m] = 0.0f; acc2[m] = 0.0f; }

#pragma unroll 4
    for (int k = 0; k < KK; ++k) {
        const float w0 = proj_w[k * EE + e0];
        const float w1 = proj_w[k * EE + e1];
        const float w2 = proj_w[k * EE + e2];
#pragma unroll
        for (int m = 0; m < MR; ++m) {
            const float sv = s[m][k];
            acc0[m] += sv * w0;
            acc1[m] += sv * w1;
            acc2[m] += sv * w2;
        }
    }

    const float pb0 = proj_b[e0], pb1 = proj_b[e1], pb2 = proj_b[e2];
#pragma unroll
    for (int m = 0; m < MR; ++m) {
        const size_t o = (size_t)(row0 + m) * EE;
        const bool p = pad[m] != 0;
        out_merge[o + e0] = p ? 0.0f : (acc0[m] + pb0);
        out_merge[o + e1] = p ? 0.0f : (acc1[m] + pb1);
        out_merge[o + e2] = p ? 0.0f : (acc2[m] + pb2);
    }
}

// ---------------- fallback: R4's fused single kernel (proven, 63.5 us) ----------------
__global__ __launch_bounds__(256) void edge_fused_kernel(
    const float* __restrict__ pos,
    const int* __restrict__ node_type_edge,
    const int* __restrict__ padding_mask,
    const int* __restrict__ mask_aa,
    const int* __restrict__ mask_pos,
    const int* __restrict__ time_pos,
    const float* __restrict__ means,
    const float* __restrict__ stds,
    const float* __restrict__ mul_w,
    const float* __restrict__ bias_w,
    const float* __restrict__ proj_w,
    const float* __restrict__ proj_b,
    const float* __restrict__ t_w1, const float* __restrict__ t_b1,
    const float* __restrict__ t_w2, const float* __restrict__ t_b2,
    float* __restrict__ out_ef,
    float* __restrict__ out_merge,
    float* __restrict__ out_dp)
{
    __shared__ float e2[2][KK];
    __shared__ float h2[2][KK];
    __shared__ float tv[2][KK];
    __shared__ float xv[NN];
    __shared__ unsigned char fl[NN];
    __shared__ float red[4 * KK];

    const int bi = blockIdx.x;
    const int b = bi >> 9;
    const int i = bi & (NN - 1);
    const int tid = threadIdx.x;

    {
        const int enc = tid >> 7;
        const int k = tid & 127;
        const float t = (enc == 0) ? (float)time_pos[b] : 0.0f;
        const int kk = k & 63;
        const float freq = __expf(-logf(10000.0f) * (float)kk * (1.0f / 64.0f));
        const float arg = t * freq;
        e2[enc][k] = (k < 64) ? cosf(arg) : sinf(arg);
        __syncthreads();

        float acc = t_b1[k];
#pragma unroll 8
        for (int r = 0; r < KK; ++r) acc += e2[enc][r] * t_w1[r * KK + k];
        h2[enc][k] = acc / (1.0f + __expf(-acc));
        __syncthreads();

        float acc2 = t_b2[k];
#pragma unroll 8
        for (int r = 0; r < KK; ++r) acc2 += h2[enc][r] * t_w2[r * KK + k];
        tv[enc][k] = 2.0f * acc2;
    }

    const float pix = pos[(b * NN + i) * 3 + 0];
    const float piy = pos[(b * NN + i) * 3 + 1];
    const float piz = pos[(b * NN + i) * 3 + 2];
    const int maa_i  = mask_aa[b * NN + i];
    const int mpos_i = mask_pos[b * NN + i];

    for (int j = tid; j < NN; j += 256) {
        const float dx = pos[(b * NN + j) * 3 + 0] - pix;
        const float dy = pos[(b * NN + j) * 3 + 1] - piy;
        const float dz = pos[(b * NN + j) * 3 + 2] - piz;
        const float dist = sqrtf(dx * dx + dy * dy + dz * dz);
        const float invd = 1.0f / (dist + 1e-5f);
        const size_t dpo = ((size_t)bi * NN + j) * 3;
        out_dp[dpo + 0] = dx * invd;
        out_dp[dpo + 1] = dy * invd;
        out_dp[dpo + 2] = dz * invd;

        const int base = (bi * NN + j) * 2;
        int e0 = node_type_edge[base + 0];
        int e1 = node_type_edge[base + 1];
        if (maa_i)               e0 = 0;
        if (mask_aa[b * NN + j]) e1 = 0;
        const float mul  = mul_w[e0]  + mul_w[e1];
        const float bias = bias_w[e0] + bias_w[e1];
        xv[j] = mul * dist + bias;

        const int md  = (mpos_i | mask_pos[b * NN + j]) ? 1 : 0;
        const int pad = padding_mask[b * NN + j] ? 2 : 0;
        fl[j] = (unsigned char)(md | pad);
    }
    __syncthreads();

    const int k0 = (tid & 63) * 2;
    const int jg = tid >> 6;
    const float a = sqrtf(2.0f * 3.14159f);

    const float mean0 = means[k0];
    const float mean1 = means[k0 + 1];
    const float sd0 = fabsf(stds[k0]) + 0.01f;
    const float sd1 = fabsf(stds[k0 + 1]) + 0.01f;
    const float inv0 = 1.0f / sd0, inv1 = 1.0f / sd1;
    const float coef0 = 1.0f / (a * sd0), coef1 = 1.0f / (a * sd1);
    const float t2_0  = tv[0][k0];
    const float t2_1  = tv[0][k0 + 1];
    const float t02_0 = tv[1][k0];
    const float t02_1 = tv[1][k0 + 1];

    float s0 = 0.0f, s1 = 0.0f;
    const size_t efbase = (size_t)bi * NN * KK;

    for (int jj = 0; jj < NN / 4; ++jj) {
        const int j = jj * 4 + jg;
        const float x = xv[j];
        const unsigned char f = fl[j];

        const float u0 = (x - mean0) * inv0;
        const float u1 = (x - mean1) * inv1;
        float v0 = __expf(-0.5f * u0 * u0) * coef0 + ((f & 1) ? t2_0 : t02_0);
        float v1 = __expf(-0.5f * u1 * u1) * coef1 + ((f & 1) ? t2_1 : t02_1);
        if (f & 2) { v0 = 0.0f; v1 = 0.0f; }
        s0 += v0; s1 += v1;

        float2 pack; pack.x = v0; pack.y = v1;
        *reinterpret_cast<float2*>(&out_ef[efbase + (size_t)j * KK + k0]) = pack;
    }

    red[jg * KK + k0]     = s0;
    red[jg * KK + k0 + 1] = s1;
    __syncthreads();

    if (tid < KK) {
        const int k = tid;
        red[k] = red[k] + red[KK + k] + red[2 * KK + k] + red[3 * KK + k];
    }
    __syncthreads();

    const bool pad_i = padding_mask[b * NN + i] != 0;
#pragma unroll
    for (int r = 0; r < 3; ++r) {
        const int e = tid + r * 256;
        float acc = proj_b[e];
#pragma unroll 16
        for (int k = 0; k < KK; ++k)
            acc += red[k] * proj_w[k * EE + e];
        out_merge[(size_t)bi * EE + e] = pad_i ? 0.0f : acc;
    }
}

extern "C" void kernel_launch(void* const* d_in, const int* in_sizes, int n_in,
                              void* d_out, int out_size, void* d_ws, size_t ws_size,
                              hipStream_t stream) {
    const float* pos          = (const float*)d_in[0];
    const int* node_type_edge = (const int*)d_in[1];
    const int* padding_mask   = (const int*)d_in[2];
    const int* mask_aa        = (const int*)d_in[3];
    const int* mask_pos       = (const int*)d_in[4];
    const int* time_pos       = (const int*)d_in[5];
    const float* means        = (const float*)d_in[6];
    const float* stds         = (const float*)d_in[7];
    const float* mul_w        = (const float*)d_in[8];
    const float* bias_w       = (const float*)d_in[9];
    const float* proj_w       = (const float*)d_in[10];
    const float* proj_b       = (const float*)d_in[11];
    const float* t_w1         = (const float*)d_in[12];
    const float* t_b1         = (const float*)d_in[13];
    const float* t_w2         = (const float*)d_in[14];
    const float* t_b2         = (const float*)d_in[15];

    float* out       = (float*)d_out;
    float* out_ef    = out;                                        // B*N*N*K
    float* out_merge = out + (size_t)BB * NN * NN * KK;            // B*N*E
    float* out_dp    = out_merge + (size_t)BB * NN * EE;           // B*N*N*3
    float* ws        = (float*)d_ws;

    if (ws_size >= WS_REQ_BYTES) {
        edge_main_kernel<<<BB * NN, 256, 0, stream>>>(
            pos, node_type_edge, padding_mask, mask_aa, mask_pos, time_pos,
            means, stds, mul_w, bias_w, t_w1, t_b1, t_w2, t_b2,
            ws, out_ef, out_dp);
        merge_tiled_kernel<<<(BB * NN) / MR, 256, 0, stream>>>(
            ws, proj_w, proj_b, padding_mask, out_merge);
    } else {
        edge_fused_kernel<<<BB * NN, 256, 0, stream>>>(
            pos, node_type_edge, padding_mask, mask_aa, mask_pos, time_pos,
            means, stds, mul_w, bias_w, proj_w, proj_b,
            t_w1, t_b1, t_w2, t_b2,
            out_ef, out_merge, out_dp);
    }
}

// Round 7
// 70.114 us; speedup vs baseline: 1.0624x; 1.0624x over previous
//
#include <hip/hip_runtime.h>
#include <hip/hip_bf16.h>
#include <math.h>

#define BB 2
#define NN 512
#define KK 128
#define EE 768
#define NUM_EDGES 1536
#define ROWS 4   // rows per persistent block; grid = B*N/ROWS = 256 = 1 block/CU

// ---------------- single persistent kernel ----------------
// 256 blocks x 256 threads. Block g owns rows bi = 4g..4g+3 (all same b).
// phase A (once): time-MLP for (t_b, t=0)
// per row: phase B (dist/delta_pos/affine) -> phase C (gaussian sweep, float2
//          stores, j-sum -> sums[r][k])
// phase D (once): merge GEMV for 4 rows, proj_w read once per block
__global__ __launch_bounds__(256) void edge_persist_kernel(
    const float* __restrict__ pos,
    const int* __restrict__ node_type_edge,
    const int* __restrict__ padding_mask,
    const int* __restrict__ mask_aa,
    const int* __restrict__ mask_pos,
    const int* __restrict__ time_pos,
    const float* __restrict__ means,
    const float* __restrict__ stds,
    const float* __restrict__ mul_w,
    const float* __restrict__ bias_w,
    const float* __restrict__ proj_w,   // [K,E]
    const float* __restrict__ proj_b,   // [E]
    const float* __restrict__ t_w1, const float* __restrict__ t_b1,
    const float* __restrict__ t_w2, const float* __restrict__ t_b2,
    float* __restrict__ out_ef,    // [B,N,N,K]
    float* __restrict__ out_merge, // [B,N,E]
    float* __restrict__ out_dp)    // [B,N,N,3]
{
    __shared__ float e2[2][KK];
    __shared__ float h2[2][KK];
    __shared__ float tv[2][KK];          // tv[0]=2*t_enc(t_b), tv[1]=2*t_enc(0)
    __shared__ float xv[NN];             // mul*dist+bias per j
    __shared__ unsigned char fl[NN];     // bit0: mask_dist, bit1: padded j
    __shared__ float red[4 * KK];        // j-group partial sums
    __shared__ float sums[ROWS][KK];     // per-row k-sums
    __shared__ int   padr[ROWS];

    const int bi0 = blockIdx.x * ROWS;
    const int b = bi0 >> 9;
    const int tid = threadIdx.x;

    // ---- phase A (once per block): threads 0..127 -> enc 0 (t=time_pos[b]),
    //      threads 128..255 -> enc 1 (t=0) ----
    {
        const int enc = tid >> 7;
        const int k = tid & 127;
        const float t = (enc == 0) ? (float)time_pos[b] : 0.0f;
        const int kk = k & 63;
        const float freq = __expf(-logf(10000.0f) * (float)kk * (1.0f / 64.0f));
        const float arg = t * freq;
        e2[enc][k] = (k < 64) ? cosf(arg) : sinf(arg);
        __syncthreads();

        float acc = t_b1[k];
#pragma unroll 8
        for (int r = 0; r < KK; ++r) acc += e2[enc][r] * t_w1[r * KK + k];
        h2[enc][k] = acc / (1.0f + __expf(-acc));   // SiLU
        __syncthreads();

        float acc2 = t_b2[k];
#pragma unroll 8
        for (int r = 0; r < KK; ++r) acc2 += h2[enc][r] * t_w2[r * KK + k];
        tv[enc][k] = 2.0f * acc2;
    }

    // per-thread phase-C constants (row-invariant)
    const int k0 = (tid & 63) * 2;
    const int jg = tid >> 6;
    const float a = sqrtf(2.0f * 3.14159f);
    const float mean0 = means[k0];
    const float mean1 = means[k0 + 1];
    const float sd0 = fabsf(stds[k0]) + 0.01f;
    const float sd1 = fabsf(stds[k0 + 1]) + 0.01f;
    const float inv0 = 1.0f / sd0, inv1 = 1.0f / sd1;
    const float coef0 = 1.0f / (a * sd0), coef1 = 1.0f / (a * sd1);
    __syncthreads();   // tv visible
    const float t2_0  = tv[0][k0];
    const float t2_1  = tv[0][k0 + 1];
    const float t02_0 = tv[1][k0];
    const float t02_1 = tv[1][k0 + 1];

    for (int r = 0; r < ROWS; ++r) {
        const int bi = bi0 + r;
        const int i = bi & (NN - 1);

        // ---- phase B: per-j quantities + delta_pos output ----
        const float pix = pos[(b * NN + i) * 3 + 0];
        const float piy = pos[(b * NN + i) * 3 + 1];
        const float piz = pos[(b * NN + i) * 3 + 2];
        const int maa_i  = mask_aa[b * NN + i];
        const int mpos_i = mask_pos[b * NN + i];

        for (int j = tid; j < NN; j += 256) {
            const float dx = pos[(b * NN + j) * 3 + 0] - pix;
            const float dy = pos[(b * NN + j) * 3 + 1] - piy;
            const float dz = pos[(b * NN + j) * 3 + 2] - piz;
            const float dist = sqrtf(dx * dx + dy * dy + dz * dz);
            const float invd = 1.0f / (dist + 1e-5f);
            const size_t dpo = ((size_t)bi * NN + j) * 3;
            out_dp[dpo + 0] = dx * invd;
            out_dp[dpo + 1] = dy * invd;
            out_dp[dpo + 2] = dz * invd;

            const int base = (bi * NN + j) * 2;
            int e0 = node_type_edge[base + 0];
            int e1 = node_type_edge[base + 1];
            if (maa_i)               e0 = 0;
            if (mask_aa[b * NN + j]) e1 = 0;
            const float mul  = mul_w[e0]  + mul_w[e1];
            const float bias = bias_w[e0] + bias_w[e1];
            xv[j] = mul * dist + bias;

            const int md  = (mpos_i | mask_pos[b * NN + j]) ? 1 : 0;
            const int pad = padding_mask[b * NN + j] ? 2 : 0;
            fl[j] = (unsigned char)(md | pad);
        }
        if (tid == 0) padr[r] = padding_mask[b * NN + i];
        __syncthreads();   // xv/fl visible

        // ---- phase C: exact R4 structure (float2 stores, 4 j-groups) ----
        float s0 = 0.0f, s1 = 0.0f;
        const size_t efbase = (size_t)bi * NN * KK;

#pragma unroll 8
        for (int jj = 0; jj < NN / 4; ++jj) {
            const int j = jj * 4 + jg;
            const float x = xv[j];
            const unsigned char f = fl[j];

            const float u0 = (x - mean0) * inv0;
            const float u1 = (x - mean1) * inv1;
            float v0 = __expf(-0.5f * u0 * u0) * coef0 + ((f & 1) ? t2_0 : t02_0);
            float v1 = __expf(-0.5f * u1 * u1) * coef1 + ((f & 1) ? t2_1 : t02_1);
            if (f & 2) { v0 = 0.0f; v1 = 0.0f; }
            s0 += v0; s1 += v1;

            float2 pack; pack.x = v0; pack.y = v1;
            *reinterpret_cast<float2*>(&out_ef[efbase + (size_t)j * KK + k0]) = pack;
        }

        red[jg * KK + k0]     = s0;
        red[jg * KK + k0 + 1] = s1;
        __syncthreads();   // red complete

        if (tid < KK)
            sums[r][tid] = red[tid] + red[KK + tid] + red[2 * KK + tid] + red[3 * KK + tid];
        __syncthreads();   // sums[r] done; safe to overwrite xv/red next row
    }

    // ---- phase D (once per block): merge GEMV for 4 rows ----
    float acc0[ROWS], acc1[ROWS], acc2[ROWS];
#pragma unroll
    for (int r = 0; r < ROWS; ++r) { acc0[r] = 0.0f; acc1[r] = 0.0f; acc2[r] = 0.0f; }

#pragma unroll 4
    for (int k = 0; k < KK; ++k) {
        const float w0 = proj_w[k * EE + tid];
        const float w1 = proj_w[k * EE + tid + 256];
        const float w2 = proj_w[k * EE + tid + 512];
#pragma unroll
        for (int r = 0; r < ROWS; ++r) {
            const float sv = sums[r][k];
            acc0[r] += sv * w0;
            acc1[r] += sv * w1;
            acc2[r] += sv * w2;
        }
    }

    const float pb0 = proj_b[tid], pb1 = proj_b[tid + 256], pb2 = proj_b[tid + 512];
#pragma unroll
    for (int r = 0; r < ROWS; ++r) {
        const size_t o = (size_t)(bi0 + r) * EE;
        const bool p = padr[r] != 0;
        out_merge[o + tid]       = p ? 0.0f : (acc0[r] + pb0);
        out_merge[o + tid + 256] = p ? 0.0f : (acc1[r] + pb1);
        out_merge[o + tid + 512] = p ? 0.0f : (acc2[r] + pb2);
    }
}

extern "C" void kernel_launch(void* const* d_in, const int* in_sizes, int n_in,
                              void* d_out, int out_size, void* d_ws, size_t ws_size,
                              hipStream_t stream) {
    const float* pos          = (const float*)d_in[0];
    const int* node_type_edge = (const int*)d_in[1];
    const int* padding_mask   = (const int*)d_in[2];
    const int* mask_aa        = (const int*)d_in[3];
    const int* mask_pos       = (const int*)d_in[4];
    const int* time_pos       = (const int*)d_in[5];
    const float* means        = (const float*)d_in[6];
    const float* stds         = (const float*)d_in[7];
    const float* mul_w        = (const float*)d_in[8];
    const float* bias_w       = (const float*)d_in[9];
    const float* proj_w       = (const float*)d_in[10];
    const float* proj_b       = (const float*)d_in[11];
    const float* t_w1         = (const float*)d_in[12];
    const float* t_b1         = (const float*)d_in[13];
    const float* t_w2         = (const float*)d_in[14];
    const float* t_b2         = (const float*)d_in[15];

    float* out       = (float*)d_out;
    float* out_ef    = out;                                        // B*N*N*K
    float* out_merge = out + (size_t)BB * NN * NN * KK;            // B*N*E
    float* out_dp    = out_merge + (size_t)BB * NN * EE;           // B*N*N*3

    edge_persist_kernel<<<(BB * NN) / ROWS, 256, 0, stream>>>(
        pos, node_type_edge, padding_mask, mask_aa, mask_pos, time_pos,
        means, stds, mul_w, bias_w, proj_w, proj_b,
        t_w1, t_b1, t_w2, t_b2,
        out_ef, out_merge, out_dp);
}